// Round 18
// baseline (459.599 us; speedup 1.0000x reference)
//
#include <hip/hip_runtime.h>

#define ZDIM 4096
#define DIN  256
#define DTS  2048
#define DOUT 256
#define CDIM 65536
#define SPLIT 16
#define NJS  8                 // j super-blocks of 32
#define NI   16                // i per chunk
#define NST  (NJS * NI)        // 128 stages per chunk
#define ZP   256               // z rows per k_bil block
#define TILE_B 8192            // HALF-tile: 128 k' x 32 j x 2B
#define CH_B  ((size_t)NST * 2 * TILE_B)   // 2 MB per chunk

typedef float fv4 __attribute__((ext_vector_type(4)));
typedef __bf16 bv8 __attribute__((ext_vector_type(8)));
typedef unsigned short u16;
typedef u16 uv8 __attribute__((ext_vector_type(8)));
typedef u16 uv4 __attribute__((ext_vector_type(4)));

union BC  { __bf16 b; u16 u; };
union VC8 { uv8 u; bv8 b; };
union FU  { unsigned u; float f; };

static __device__ __forceinline__ u16  f2b(float f){ BC c; c.b=(__bf16)f; return c.u; }
static __device__ __forceinline__ float bu(u16 v){ FU c; c.u = ((unsigned)v) << 16; return c.f; }
static __device__ __forceinline__ bv8  asb(uv8 x){ VC8 c; c.u=x; return c.b; }
static __device__ __forceinline__ uv8  pack8(fv4 a, fv4 b){
  uv8 p;
  p[0]=f2b(a[0]); p[1]=f2b(a[1]); p[2]=f2b(a[2]); p[3]=f2b(a[3]);
  p[4]=f2b(b[0]); p[5]=f2b(b[1]); p[6]=f2b(b[2]); p[7]=f2b(b[3]);
  return p;
}

// Km layout: chunk s (2MB) -> stage st (16KB pair) -> half kh (8KB):
//   byte = s*CH_B + (st*2+kh)*TILE_B + e,  e = k'*64 + jj*2,
//   e ^= ((e>>7)&7)<<4   (bank swizzle for the b128 reads)

// ---------------------------------------------------------------------------
// Kernel 1 v6: Kmat = W @ T -> bf16 tiled+swizzled.
// vs champion (R14/R17): Al deleted (af direct from global f32 W, L2-hot,
// issued BEFORE T loads so the af-wait vmcnt(2) keeps T in flight);
// Bl double-buffered write-late with pad 130 (2-way banks, was 8-way at 128);
// ONE barrier/stage (was 2). bf16 B-path (pack8 on stage) kept verbatim.
// ---------------------------------------------------------------------------
__global__ __launch_bounds__(512, 2) void k_wt(const float* __restrict__ W,
                                               const float* __restrict__ T,
                                               u16* __restrict__ Km) {
  __shared__ u16 Bl[2][32 * 130];
  const int tid  = threadIdx.x;
  const int lane = tid & 63;
  const int wave = tid >> 6;
  const int wk = (wave >> 1) * 64;
  const int wc = (wave & 1) * 64;
  const int cb = blockIdx.x * 128;
  const int ar = lane & 15, tg = lane >> 4;
  const int tr = tid >> 4, co = (tid & 15) * 8;   // T staging map

  // prologue: stage T tile 0 into Bl[0]
  {
    const float* src = T + (size_t)tr * CDIM + cb + co;
    *(uv8*)&Bl[0][tr * 130 + co] = pack8(*(const fv4*)src, *(const fv4*)(src + 4));
  }
  __syncthreads();

  fv4 acc[4][4];
#pragma unroll
  for (int m = 0; m < 4; ++m)
#pragma unroll
    for (int n = 0; n < 4; ++n)
#pragma unroll
      for (int r = 0; r < 4; ++r) acc[m][n][r] = 0.f;

  int buf = 0;
  for (int st = 0; st < 64; ++st) {
    const int t0 = st * 32;
    // (1) af loads FIRST: W f32 -> bf16 frags (L2-hot after first c-block)
    bv8 af[4];
#pragma unroll
    for (int m = 0; m < 4; ++m) {
      const float* wsrc = W + (size_t)(wk + m * 16 + ar) * DTS + t0 + tg * 8;
      af[m] = asb(pack8(*(const fv4*)wsrc, *(const fv4*)(wsrc + 4)));
    }
    // (2) T(st+1) loads SECOND: stay outstanding through the af-wait
    const bool stg = (st < 63);
    fv4 ta, tb;
    if (stg) {
      const float* src = T + (size_t)(t0 + 32 + tr) * CDIM + cb + co;
      ta = *(const fv4*)src; tb = *(const fv4*)(src + 4);
    }
    // (3) MFMAs on Bl[buf] (pad-130: 2-way banks = free)
#pragma unroll
    for (int n = 0; n < 4; ++n) {
      uv8 bu2;
#pragma unroll
      for (int e = 0; e < 8; ++e)
        bu2[e] = Bl[buf][(tg * 8 + e) * 130 + wc + n * 16 + ar];
      bv8 bf = asb(bu2);
#pragma unroll
      for (int m = 0; m < 4; ++m)
        acc[m][n] = __builtin_amdgcn_mfma_f32_16x16x32_bf16(af[m], bf, acc[m][n], 0, 0, 0);
    }
    // (4) write-late into the other buffer; ONE barrier
    if (stg)
      *(uv8*)&Bl[buf ^ 1][tr * 130 + co] = pack8(ta, tb);
    __syncthreads();
    buf ^= 1;
  }

  // epilogue: half-k tiled + swizzled (unchanged)
  const int ig = cb >> 8;
  const int j0 = cb & 255;
#pragma unroll
  for (int m = 0; m < 4; ++m)
#pragma unroll
    for (int n = 0; n < 4; ++n) {
      int j  = j0 + wc + n * 16;
      int js = j >> 5;
      int jj = j & 31;
      int sc = ig >> 4, il = ig & 15;
#pragma unroll
      for (int r = 0; r < 4; ++r) {
        int kr = wk + m * 16 + tg * 4 + r;
        int kh = kr >> 7, kp = kr & 127;
        size_t tb2 = (size_t)sc * CH_B +
                     (size_t)((js * 16 + il) * 2 + kh) * TILE_B;
        int e = kp * 64 + (jj + ar) * 2;
        e ^= ((e >> 7) & 7) << 4;
        *(u16*)((char*)Km + tb2 + e) = f2b(acc[m][n][r]);
      }
    }
}

// ---------------------------------------------------------------------------
// Kernel 2 v12 (champion, unchanged): 512-thread blocks + k-split,
// 4-buffer depth-3 counted-vmcnt pipeline on contiguous 8KB half-tiles.
// ---------------------------------------------------------------------------
__global__ __launch_bounds__(512, 2) void k_bil(const float* __restrict__ X,
                                                const u16* __restrict__ Km,
                                                u16* __restrict__ P) {
  __shared__ u16 Kl[4 * 4096];    // 32KB: 4 x 8KB half-tiles
  __shared__ float Xt[16 * 256];  // 16KB: f32 Xt[i][z]
  const int tid  = threadIdx.x;
  const int lane = tid & 63;
  const int wave = tid >> 6;
  const int wz   = (wave >> 1) * 64;
  const int wkp  = (wave & 1) * 64;
  const int bid  = blockIdx.x;
  const int s    = bid & 15;
  const int kh   = (bid >> 4) & 1;
  const int z0   = (bid >> 5) * ZP;
  const int i0   = s * NI;
  const int ar   = lane & 15, tg = lane >> 4;

  const char* chunk = (const char*)Km + (size_t)s * CH_B;
#define TOFF(t) ((size_t)(((t) * 2) + kh) * TILE_B)

  for (int idx = tid; idx < 16 * 256; idx += 512) {
    int ii = idx >> 8, z = idx & 255;
    Xt[idx] = X[(size_t)(z0 + z) * DIN + i0 + ii];
  }
#pragma unroll
  for (int t = 0; t < 3; ++t)
    __builtin_amdgcn_global_load_lds(
        (const __attribute__((address_space(1))) void*)(chunk + TOFF(t) + (size_t)tid * 16),
        (__attribute__((address_space(3))) void*)((char*)Kl + t * TILE_B + tid * 16), 16, 0, 0);
  __syncthreads();

  int boff[4], xoff[4];
#pragma unroll
  for (int n = 0; n < 4; ++n) {
    int kpp = wkp + n * 16 + ar;
    int e = kpp * 64 + tg * 16;
    boff[n] = e ^ (((e >> 7) & 7) << 4);
  }
#pragma unroll
  for (int m = 0; m < 4; ++m) xoff[m] = wz + m * 16 + ar;

  fv4 acc[4][4];
#pragma unroll
  for (int m = 0; m < 4; ++m)
#pragma unroll
    for (int n = 0; n < 4; ++n)
#pragma unroll
      for (int r = 0; r < 4; ++r) acc[m][n][r] = 0.f;

  int ca = 0, cd = 3;

#define KB_ITER(ST, II, ISSUE, BARW)                                            \
  {                                                                             \
    if (ISSUE)                                                                  \
      __builtin_amdgcn_global_load_lds(                                         \
          (const __attribute__((address_space(1))) void*)(chunk +               \
              TOFF((ST) + 3) + (size_t)tid * 16),                               \
          (__attribute__((address_space(3))) void*)((char*)Kl +                 \
              cd * TILE_B + tid * 16), 16, 0, 0);                               \
    uv8 ap_[4];                                                                 \
    _Pragma("unroll")                                                           \
    for (int m_ = 0; m_ < 4; ++m_) {                                            \
      float xi_ = Xt[(II) * 256 + xoff[m_]];                                    \
      _Pragma("unroll")                                                         \
      for (int e_ = 0; e_ < 8; ++e_) ap_[m_][e_] = f2b(xi_ * bu(af[m_][e_]));   \
    }                                                                           \
    _Pragma("unroll")                                                           \
    for (int n_ = 0; n_ < 4; ++n_) {                                            \
      bv8 bf_ = asb(*(const uv8*)((const char*)Kl + ca * TILE_B + boff[n_]));   \
      _Pragma("unroll")                                                         \
      for (int m_ = 0; m_ < 4; ++m_)                                            \
        acc[m_][n_] = __builtin_amdgcn_mfma_f32_16x16x32_bf16(                  \
            asb(ap_[m_]), bf_, acc[m_][n_], 0, 0, 0);                           \
    }                                                                           \
    if ((BARW) >= 0) {                                                          \
      if ((BARW) == 2)      asm volatile("s_waitcnt vmcnt(2)" ::: "memory");    \
      else if ((BARW) == 1) asm volatile("s_waitcnt vmcnt(1)" ::: "memory");    \
      else                  asm volatile("s_waitcnt vmcnt(0)" ::: "memory");    \
      __builtin_amdgcn_s_barrier();                                             \
      asm volatile("" ::: "memory");                                            \
    }                                                                           \
    ca = (ca + 1) & 3; cd = (cd + 1) & 3;                                       \
  }

  for (int js = 0; js < 7; ++js) {
    uv8 af[4];
#pragma unroll
    for (int m = 0; m < 4; ++m) {
      const float* row = X + (size_t)(z0 + wz + m * 16 + ar) * DIN + js * 32 + tg * 8;
      af[m] = pack8(*(const fv4*)row, *(const fv4*)(row + 4));
    }
#pragma unroll
    for (int i = 0; i < 16; ++i) KB_ITER(js * 16 + i, i, true, 2)
  }
  {   // js = 7, tail-peeled (last issue at st=124 -> stage 127)
    uv8 af[4];
#pragma unroll
    for (int m = 0; m < 4; ++m) {
      const float* row = X + (size_t)(z0 + wz + m * 16 + ar) * DIN + 7 * 32 + tg * 8;
      af[m] = pack8(*(const fv4*)row, *(const fv4*)(row + 4));
    }
#pragma unroll
    for (int i = 0; i < 13; ++i) KB_ITER(112 + i, i, true, 2)
    KB_ITER(125, 13, false, 1)
    KB_ITER(126, 14, false, 0)
    KB_ITER(127, 15, false, -1)
  }
#undef KB_ITER
#undef TOFF

  u16* dst = P + (size_t)s * (ZDIM * DOUT) + (size_t)z0 * DOUT + kh * 128;
#pragma unroll
  for (int m = 0; m < 4; ++m)
#pragma unroll
    for (int n = 0; n < 4; ++n)
#pragma unroll
      for (int r = 0; r < 4; ++r)
        dst[(size_t)(wz + m * 16 + tg * 4 + r) * DOUT + wkp + n * 16 + ar] =
            f2b(acc[m][n][r]);
}

// ---------------------------------------------------------------------------
// Kernel 3: out[z][k] = sum_s bf16 partial[s][z][k]
// ---------------------------------------------------------------------------
__global__ __launch_bounds__(256) void k_red(const u16* __restrict__ P,
                                             float* __restrict__ O) {
  size_t idx = ((size_t)blockIdx.x * 256 + threadIdx.x) * 4;
  fv4 acc;
#pragma unroll
  for (int r = 0; r < 4; ++r) acc[r] = 0.f;
#pragma unroll
  for (int p = 0; p < SPLIT; ++p) {
    uv4 v = *(const uv4*)&P[(size_t)p * (ZDIM * DOUT) + idx];
#pragma unroll
    for (int r = 0; r < 4; ++r) acc[r] += bu(v[r]);
  }
  *(fv4*)&O[idx] = acc;
}

extern "C" void kernel_launch(void* const* d_in, const int* in_sizes, int n_in,
                              void* d_out, int out_size, void* d_ws, size_t ws_size,
                              hipStream_t stream) {
  const float* feat = (const float*)d_in[0];   // [4096, 256]
  const float* T    = (const float*)d_in[1];   // [2048, 65536]
  const float* W    = (const float*)d_in[2];   // [256, 2048]
  float* out = (float*)d_out;                  // [4096, 256]

  u16* Km = (u16*)d_ws;                                      // 32 MB bf16 tiled Kmat
  u16* P  = (u16*)((char*)d_ws + (size_t)DOUT * CDIM * 2);   // 32 MB bf16 partials

  k_wt <<<dim3(512),  dim3(512), 0, stream>>>(W, T, Km);
  k_bil<<<dim3(512),  dim3(512), 0, stream>>>(feat, Km, P);
  k_red<<<dim3(1024), dim3(256), 0, stream>>>(P, out);
}

// Round 19
// 321.652 us; speedup vs baseline: 1.4289x; 1.4289x over previous
//
#include <hip/hip_runtime.h>

#define ZDIM 4096
#define DIN  256
#define DTS  2048
#define DOUT 256
#define CDIM 65536
#define SPLIT 16
#define NJS  8                 // j super-blocks of 32
#define NI   16                // i per chunk
#define NST  (NJS * NI)        // 128 stages per chunk
#define ZP   256               // z rows per k_bil block
#define TILE_B 8192            // HALF-tile: 128 k' x 32 j x 2B
#define CH_B  ((size_t)NST * 2 * TILE_B)   // 2 MB per chunk

typedef float fv4 __attribute__((ext_vector_type(4)));
typedef __bf16 bv8 __attribute__((ext_vector_type(8)));
typedef unsigned short u16;
typedef u16 uv8 __attribute__((ext_vector_type(8)));
typedef u16 uv4 __attribute__((ext_vector_type(4)));

union BC  { __bf16 b; u16 u; };
union VC8 { uv8 u; bv8 b; };
union FU  { unsigned u; float f; };

static __device__ __forceinline__ u16  f2b(float f){ BC c; c.b=(__bf16)f; return c.u; }
static __device__ __forceinline__ float bu(u16 v){ FU c; c.u = ((unsigned)v) << 16; return c.f; }
static __device__ __forceinline__ bv8  asb(uv8 x){ VC8 c; c.u=x; return c.b; }
static __device__ __forceinline__ uv8  pack8(fv4 a, fv4 b){
  uv8 p;
  p[0]=f2b(a[0]); p[1]=f2b(a[1]); p[2]=f2b(a[2]); p[3]=f2b(a[3]);
  p[4]=f2b(b[0]); p[5]=f2b(b[1]); p[6]=f2b(b[2]); p[7]=f2b(b[3]);
  return p;
}

// Km layout: chunk s (2MB) -> stage st (16KB pair) -> half kh (8KB):
//   byte = s*CH_B + (st*2+kh)*TILE_B + e,  e = k'*64 + jj*2,
//   e ^= ((e>>7)&7)<<4   (bank swizzle for the b128 reads)

// ---------------------------------------------------------------------------
// Kernel 1: champion body (R14/R17: Al+Bl, 2 barriers) with ONE change:
// Bl row stride 128 -> 130.  B-frag scalar reads go 8-way-conflicted ->
// 2-way (free): bank = (tg*8+e + n*8 + ar/2) & 31 covers all 32 banks.
// ---------------------------------------------------------------------------
__global__ __launch_bounds__(512, 2) void k_wt(const float* __restrict__ W,
                                               const float* __restrict__ T,
                                               u16* __restrict__ Km) {
  __shared__ u16 Al[256 * 40];
  __shared__ u16 Bl[32 * 130];
  const int tid  = threadIdx.x;
  const int lane = tid & 63;
  const int wave = tid >> 6;
  const int wk = (wave >> 1) * 64;
  const int wc = (wave & 1) * 64;
  const int cb = blockIdx.x * 128;
  const int ar = lane & 15, tg = lane >> 4;

  fv4 acc[4][4];
#pragma unroll
  for (int m = 0; m < 4; ++m)
#pragma unroll
    for (int n = 0; n < 4; ++n)
#pragma unroll
      for (int r = 0; r < 4; ++r) acc[m][n][r] = 0.f;

  for (int t0 = 0; t0 < DTS; t0 += 32) {
#pragma unroll
    for (int p = 0; p < 2; ++p) {
      int oct = tid + p * 512;
      int kr = oct >> 2, ts = (oct & 3) * 8;
      const float* src = W + (size_t)kr * DTS + t0 + ts;
      fv4 a = *(const fv4*)src, b = *(const fv4*)(src + 4);
      *(uv8*)&Al[kr * 40 + ts] = pack8(a, b);
    }
    {
      int tr = tid >> 4, co = (tid & 15) * 8;
      const float* src = T + (size_t)(t0 + tr) * CDIM + cb + co;
      fv4 a = *(const fv4*)src, b = *(const fv4*)(src + 4);
      *(uv8*)&Bl[tr * 130 + co] = pack8(a, b);
    }
    __syncthreads();
    bv8 af[4];
#pragma unroll
    for (int m = 0; m < 4; ++m)
      af[m] = asb(*(const uv8*)&Al[(wk + m * 16 + ar) * 40 + tg * 8]);
#pragma unroll
    for (int n = 0; n < 4; ++n) {
      uv8 bu2;
#pragma unroll
      for (int e = 0; e < 8; ++e)
        bu2[e] = Bl[(tg * 8 + e) * 130 + wc + n * 16 + ar];
      bv8 bf = asb(bu2);
#pragma unroll
      for (int m = 0; m < 4; ++m)
        acc[m][n] = __builtin_amdgcn_mfma_f32_16x16x32_bf16(af[m], bf, acc[m][n], 0, 0, 0);
    }
    __syncthreads();
  }
  // epilogue: half-k tiled + swizzled
  const int ig = cb >> 8;            // i_glob
  const int j0 = cb & 255;
#pragma unroll
  for (int m = 0; m < 4; ++m)
#pragma unroll
    for (int n = 0; n < 4; ++n) {
      int j  = j0 + wc + n * 16;
      int js = j >> 5;
      int jj = j & 31;               // +ar stays < 32
      int sc = ig >> 4, il = ig & 15;
#pragma unroll
      for (int r = 0; r < 4; ++r) {
        int kr = wk + m * 16 + tg * 4 + r;
        int kh = kr >> 7, kp = kr & 127;
        size_t tb = (size_t)sc * CH_B +
                    (size_t)((js * 16 + il) * 2 + kh) * TILE_B;
        int e = kp * 64 + (jj + ar) * 2;
        e ^= ((e >> 7) & 7) << 4;
        *(u16*)((char*)Km + tb + e) = f2b(acc[m][n][r]);
      }
    }
}

// ---------------------------------------------------------------------------
// Kernel 2 v12 (champion, unchanged): 512-thread blocks + k-split,
// 4-buffer depth-3 counted-vmcnt pipeline on contiguous 8KB half-tiles.
// ---------------------------------------------------------------------------
__global__ __launch_bounds__(512, 2) void k_bil(const float* __restrict__ X,
                                                const u16* __restrict__ Km,
                                                u16* __restrict__ P) {
  __shared__ u16 Kl[4 * 4096];    // 32KB: 4 x 8KB half-tiles
  __shared__ float Xt[16 * 256];  // 16KB: f32 Xt[i][z]
  const int tid  = threadIdx.x;
  const int lane = tid & 63;
  const int wave = tid >> 6;
  const int wz   = (wave >> 1) * 64;
  const int wkp  = (wave & 1) * 64;
  const int bid  = blockIdx.x;
  const int s    = bid & 15;
  const int kh   = (bid >> 4) & 1;
  const int z0   = (bid >> 5) * ZP;
  const int i0   = s * NI;
  const int ar   = lane & 15, tg = lane >> 4;

  const char* chunk = (const char*)Km + (size_t)s * CH_B;
#define TOFF(t) ((size_t)(((t) * 2) + kh) * TILE_B)

  for (int idx = tid; idx < 16 * 256; idx += 512) {
    int ii = idx >> 8, z = idx & 255;
    Xt[idx] = X[(size_t)(z0 + z) * DIN + i0 + ii];
  }
#pragma unroll
  for (int t = 0; t < 3; ++t)
    __builtin_amdgcn_global_load_lds(
        (const __attribute__((address_space(1))) void*)(chunk + TOFF(t) + (size_t)tid * 16),
        (__attribute__((address_space(3))) void*)((char*)Kl + t * TILE_B + tid * 16), 16, 0, 0);
  __syncthreads();

  int boff[4], xoff[4];
#pragma unroll
  for (int n = 0; n < 4; ++n) {
    int kpp = wkp + n * 16 + ar;
    int e = kpp * 64 + tg * 16;
    boff[n] = e ^ (((e >> 7) & 7) << 4);
  }
#pragma unroll
  for (int m = 0; m < 4; ++m) xoff[m] = wz + m * 16 + ar;

  fv4 acc[4][4];
#pragma unroll
  for (int m = 0; m < 4; ++m)
#pragma unroll
    for (int n = 0; n < 4; ++n)
#pragma unroll
      for (int r = 0; r < 4; ++r) acc[m][n][r] = 0.f;

  int ca = 0, cd = 3;

#define KB_ITER(ST, II, ISSUE, BARW)                                            \
  {                                                                             \
    if (ISSUE)                                                                  \
      __builtin_amdgcn_global_load_lds(                                         \
          (const __attribute__((address_space(1))) void*)(chunk +               \
              TOFF((ST) + 3) + (size_t)tid * 16),                               \
          (__attribute__((address_space(3))) void*)((char*)Kl +                 \
              cd * TILE_B + tid * 16), 16, 0, 0);                               \
    uv8 ap_[4];                                                                 \
    _Pragma("unroll")                                                           \
    for (int m_ = 0; m_ < 4; ++m_) {                                            \
      float xi_ = Xt[(II) * 256 + xoff[m_]];                                    \
      _Pragma("unroll")                                                         \
      for (int e_ = 0; e_ < 8; ++e_) ap_[m_][e_] = f2b(xi_ * bu(af[m_][e_]));   \
    }                                                                           \
    _Pragma("unroll")                                                           \
    for (int n_ = 0; n_ < 4; ++n_) {                                            \
      bv8 bf_ = asb(*(const uv8*)((const char*)Kl + ca * TILE_B + boff[n_]));   \
      _Pragma("unroll")                                                         \
      for (int m_ = 0; m_ < 4; ++m_)                                            \
        acc[m_][n_] = __builtin_amdgcn_mfma_f32_16x16x32_bf16(                  \
            asb(ap_[m_]), bf_, acc[m_][n_], 0, 0, 0);                           \
    }                                                                           \
    if ((BARW) >= 0) {                                                          \
      if ((BARW) == 2)      asm volatile("s_waitcnt vmcnt(2)" ::: "memory");    \
      else if ((BARW) == 1) asm volatile("s_waitcnt vmcnt(1)" ::: "memory");    \
      else                  asm volatile("s_waitcnt vmcnt(0)" ::: "memory");    \
      __builtin_amdgcn_s_barrier();                                             \
      asm volatile("" ::: "memory");                                            \
    }                                                                           \
    ca = (ca + 1) & 3; cd = (cd + 1) & 3;                                       \
  }

  for (int js = 0; js < 7; ++js) {
    uv8 af[4];
#pragma unroll
    for (int m = 0; m < 4; ++m) {
      const float* row = X + (size_t)(z0 + wz + m * 16 + ar) * DIN + js * 32 + tg * 8;
      af[m] = pack8(*(const fv4*)row, *(const fv4*)(row + 4));
    }
#pragma unroll
    for (int i = 0; i < 16; ++i) KB_ITER(js * 16 + i, i, true, 2)
  }
  {   // js = 7, tail-peeled (last issue at st=124 -> stage 127)
    uv8 af[4];
#pragma unroll
    for (int m = 0; m < 4; ++m) {
      const float* row = X + (size_t)(z0 + wz + m * 16 + ar) * DIN + 7 * 32 + tg * 8;
      af[m] = pack8(*(const fv4*)row, *(const fv4*)(row + 4));
    }
#pragma unroll
    for (int i = 0; i < 13; ++i) KB_ITER(112 + i, i, true, 2)
    KB_ITER(125, 13, false, 1)
    KB_ITER(126, 14, false, 0)
    KB_ITER(127, 15, false, -1)
  }
#undef KB_ITER
#undef TOFF

  u16* dst = P + (size_t)s * (ZDIM * DOUT) + (size_t)z0 * DOUT + kh * 128;
#pragma unroll
  for (int m = 0; m < 4; ++m)
#pragma unroll
    for (int n = 0; n < 4; ++n)
#pragma unroll
      for (int r = 0; r < 4; ++r)
        dst[(size_t)(wz + m * 16 + tg * 4 + r) * DOUT + wkp + n * 16 + ar] =
            f2b(acc[m][n][r]);
}

// ---------------------------------------------------------------------------
// Kernel 3: out[z][k] = sum_s bf16 partial[s][z][k]
// ---------------------------------------------------------------------------
__global__ __launch_bounds__(256) void k_red(const u16* __restrict__ P,
                                             float* __restrict__ O) {
  size_t idx = ((size_t)blockIdx.x * 256 + threadIdx.x) * 4;
  fv4 acc;
#pragma unroll
  for (int r = 0; r < 4; ++r) acc[r] = 0.f;
#pragma unroll
  for (int p = 0; p < SPLIT; ++p) {
    uv4 v = *(const uv4*)&P[(size_t)p * (ZDIM * DOUT) + idx];
#pragma unroll
    for (int r = 0; r < 4; ++r) acc[r] += bu(v[r]);
  }
  *(fv4*)&O[idx] = acc;
}

extern "C" void kernel_launch(void* const* d_in, const int* in_sizes, int n_in,
                              void* d_out, int out_size, void* d_ws, size_t ws_size,
                              hipStream_t stream) {
  const float* feat = (const float*)d_in[0];   // [4096, 256]
  const float* T    = (const float*)d_in[1];   // [2048, 65536]
  const float* W    = (const float*)d_in[2];   // [256, 2048]
  float* out = (float*)d_out;                  // [4096, 256]

  u16* Km = (u16*)d_ws;                                      // 32 MB bf16 tiled Kmat
  u16* P  = (u16*)((char*)d_ws + (size_t)DOUT * CDIM * 2);   // 32 MB bf16 partials

  k_wt <<<dim3(512),  dim3(512), 0, stream>>>(W, T, Km);
  k_bil<<<dim3(512),  dim3(512), 0, stream>>>(feat, Km, P);
  k_red<<<dim3(1024), dim3(256), 0, stream>>>(P, out);
}